// Round 2
// baseline (41368.912 us; speedup 1.0000x reference)
//
#include <hip/hip_runtime.h>
#include <hip/hip_bf16.h>
#include <math.h>

#define BB 64
#define SS 512
#define EE 256
#define HH 512
#define GG 2048   // 4H
#define NWG 256

// ---------------------------------------------------------------------------
// K_pre: fold dense + CRF kernel:  wde[tag][k] = sum_m Wd[k][m]*crfW[m][tag]
//        bde[tag] = sum_m bd[m]*crfW[m][tag] + crfb[tag]
// ---------------------------------------------------------------------------
__global__ void k_wde(const float* __restrict__ Wd, const float* __restrict__ bd,
                      const float* __restrict__ crfW, const float* __restrict__ crfb,
                      float* __restrict__ wde, float* __restrict__ bde)
{
  const int idx = blockIdx.x*256 + threadIdx.x;
  if (idx < 9*1024) {
    const int tag = idx >> 10, k = idx & 1023;
    float s = 0.f;
    #pragma unroll
    for (int m = 0; m < 9; ++m) s += Wd[k*9 + m] * crfW[m*9 + tag];
    wde[idx] = s;
  }
  if (idx < 9) {
    float s = crfb[idx];
    #pragma unroll
    for (int m = 0; m < 9; ++m) s += bd[m]*crfW[m*9 + idx];
    bde[idx] = s;
  }
}

// ---------------------------------------------------------------------------
// K2: persistent fused bidirectional LSTM. 256 WGs = 2 dir x 128 col-chunks
// (4 h-cols each), 256 threads. Embedding gather + x@W fused in-kernel (no
// xw buffer => workspace is just hall, ~134.5 MB). U slice in VGPRs (128),
// W slice in LDS (16 KB, bank-uniform layout). h staged via LDS in 128-k
// chunks; per-step device-wide tree barrier (agent-scope atomics).
// h_all[d][phase 0..512][b][512]; phase 0 = zeros (memset by host).
// ---------------------------------------------------------------------------
__global__ __launch_bounds__(256, 1) void k_lstm(
    const int* __restrict__ inputs, const float* __restrict__ emb,
    const float* __restrict__ Uf, const float* __restrict__ Ub,
    const float* __restrict__ Wf, const float* __restrict__ Wb,
    const float* __restrict__ bf, const float* __restrict__ bb2,
    float* __restrict__ h_all, unsigned int* __restrict__ bars)
{
  const int wg   = blockIdx.x;
  const int d    = wg >> 7;
  const int cblk = wg & 127;                 // h-cols cblk*4 .. +3
  const float* __restrict__ U    = d ? Ub  : Uf;
  const float* __restrict__ W    = d ? Wb  : Wf;
  const float* __restrict__ bias = d ? bb2 : bf;
  float* __restrict__ h_d = h_all + (size_t)d * ((size_t)(SS+1)*BB*HH);

  __shared__ float smem[10240];   // overlay: chunk [64 b][128 k] (32KB) / pbuf [512][20] (40KB)
  __shared__ float Wl[4096];      // [cn][i][kcc][jj][g] -> bank-uniform b128 reads
  __shared__ int   tok_l[64];

  const int tid  = threadIdx.x;
  const int bq   = tid >> 6;        // wave id = b quarter
  const int lane = tid & 63;
  const int kcc  = lane & 15;       // 16-way k split
  const int jj   = lane >> 4;       // which of the 4 h-cols

  // stage W slice once: Wl[cn*2048 + i*256 + kcc*16 + jj*4 + g]
  for (int e = 0; e < 16; ++e) {
    const int idx = tid*16 + e;
    const int g   = idx & 3;
    const int j2  = (idx >> 2) & 3;
    const int kc2 = (idx >> 4) & 15;
    const int i2  = (idx >> 8) & 7;
    const int cn2 = (idx >> 11) & 1;
    const int k   = cn2*128 + kc2*8 + i2;
    Wl[idx] = W[(size_t)k*GG + g*512 + cblk*4 + j2];
  }

  // U in registers: ureg[cn*8+i] = gates (i,f,g,o) at k=cn*128+kcc*8+i, col cblk*4+jj
  float4 ureg[32];
  #pragma unroll
  for (int cn = 0; cn < 4; ++cn)
    #pragma unroll
    for (int i = 0; i < 8; ++i) {
      const int k = cn*128 + kcc*8 + i;
      const float* ur = U + (size_t)k*GG + cblk*4 + jj;
      ureg[cn*8+i] = make_float4(ur[0], ur[512], ur[1024], ur[1536]);
    }

  // gate-phase statics (threads 0..127 own (b,col) pairs, fixed across steps)
  const int gq  = tid >> 5;        // 0..3
  const int gbl = (tid >> 2) & 7;  // 0..7
  const int gj  = tid & 3;         // col within chunk
  float bb[4] = {0.f,0.f,0.f,0.f};
  if (tid < 128) {
    #pragma unroll
    for (int g = 0; g < 4; ++g) bb[g] = bias[g*512 + cblk*4 + gj];
  }
  float cst0 = 0.f, cst1 = 0.f;    // c-state for b-half 0 / 1

  for (int p = 0; p < 512; ++p) {
    const int t = d ? (511 - p) : p;
    const float* __restrict__ hprev = h_d + (size_t)p     * (size_t)(BB*HH);
    float* __restrict__ hnext       = h_d + (size_t)(p+1) * (size_t)(BB*HH);

    if (tid < 64) tok_l[tid] = inputs[tid*SS + t];

    float part[16][4];
    #pragma unroll
    for (int bl=0;bl<16;++bl) { part[bl][0]=0.f; part[bl][1]=0.f; part[bl][2]=0.f; part[bl][3]=0.f; }

    // 6 chunks: cn 0..1 = x@W (K=256), cn 2..5 = h@U (K=512)
    #pragma unroll
    for (int cn = 0; cn < 6; ++cn) {
      __syncthreads();
      {  // stage chunk [64 b][128 k] into smem, bank-uniform writes
        const int bbase = tid >> 5;        // 0..7
        const int kk    = (tid & 31) * 4;
        #pragma unroll
        for (int j = 0; j < 8; ++j) {
          const int b = j*8 + bbase;
          float4 v;
          if (cn < 2) v = *(const float4*)&emb[(size_t)tok_l[b]*EE + cn*128 + kk];
          else        v = *(const float4*)&hprev[(size_t)b*HH + (cn-2)*128 + kk];
          *(float4*)&smem[j*1024 + tid*4] = v;
        }
      }
      __syncthreads();
      if (cn < 2) {
        float4 wv[8];
        #pragma unroll
        for (int i = 0; i < 8; ++i)
          wv[i] = *(const float4*)&Wl[cn*2048 + i*256 + kcc*16 + jj*4];
        #pragma unroll
        for (int bl = 0; bl < 16; ++bl) {
          const float* hrow = &smem[(bq*16 + bl)*128 + kcc*8];
          const float4 ha = *(const float4*)hrow;
          const float4 hb = *(const float4*)(hrow + 4);
          const float hv[8] = {ha.x,ha.y,ha.z,ha.w,hb.x,hb.y,hb.z,hb.w};
          #pragma unroll
          for (int i = 0; i < 8; ++i) {
            part[bl][0] += hv[i]*wv[i].x;
            part[bl][1] += hv[i]*wv[i].y;
            part[bl][2] += hv[i]*wv[i].z;
            part[bl][3] += hv[i]*wv[i].w;
          }
        }
      } else {
        #pragma unroll
        for (int bl = 0; bl < 16; ++bl) {
          const float* hrow = &smem[(bq*16 + bl)*128 + kcc*8];
          const float4 ha = *(const float4*)hrow;
          const float4 hb = *(const float4*)(hrow + 4);
          const float hv[8] = {ha.x,ha.y,ha.z,ha.w,hb.x,hb.y,hb.z,hb.w};
          #pragma unroll
          for (int i = 0; i < 8; ++i) {
            const float4 u = ureg[(cn-2)*8 + i];
            part[bl][0] += hv[i]*u.x;
            part[bl][1] += hv[i]*u.y;
            part[bl][2] += hv[i]*u.z;
            part[bl][3] += hv[i]*u.w;
          }
        }
      }
    }

    // reduce 16 k-partials + gates, two b-halves (pbuf overlays smem)
    #pragma unroll
    for (int h = 0; h < 2; ++h) {
      __syncthreads();
      #pragma unroll
      for (int bl = 0; bl < 8; ++bl) {
        const int row = (bq*8 + bl)*16;
        #pragma unroll
        for (int g = 0; g < 4; ++g)
          smem[(row + g*4 + jj)*20 + kcc] = part[h*8 + bl][g];
      }
      __syncthreads();
      if (tid < 128) {
        const int b = gq*16 + h*8 + gbl;
        float z[4];
        #pragma unroll
        for (int g = 0; g < 4; ++g) {
          const float* pr = &smem[((gq*8 + gbl)*16 + g*4 + gj)*20];
          const float4 s0 = *(const float4*)pr;
          const float4 s1 = *(const float4*)(pr+4);
          const float4 s2 = *(const float4*)(pr+8);
          const float4 s3 = *(const float4*)(pr+12);
          z[g] = ((s0.x+s0.y)+(s0.z+s0.w)) + ((s1.x+s1.y)+(s1.z+s1.w))
               + ((s2.x+s2.y)+(s2.z+s2.w)) + ((s3.x+s3.y)+(s3.z+s3.w)) + bb[g];
        }
        const float ig = 1.f/(1.f + expf(-z[0]));
        const float fg = 1.f/(1.f + expf(-z[1]));
        const float tg = tanhf(z[2]);
        const float og = 1.f/(1.f + expf(-z[3]));
        float cs = h ? cst1 : cst0;
        cs = fg*cs + ig*tg;
        if (h) cst1 = cs; else cst0 = cs;
        hnext[(size_t)b*HH + cblk*4 + gj] = og * tanhf(cs);
      }
    }

    // device-wide barrier (8 group counters of 32 WGs -> root)
    __threadfence();
    __syncthreads();
    if (tid == 0) {
      const int g = wg & 7;
      const unsigned int old = __hip_atomic_fetch_add(&bars[16 + g*16], 1u,
                                 __ATOMIC_ACQ_REL, __HIP_MEMORY_SCOPE_AGENT);
      if ((old & 31u) == 31u)
        __hip_atomic_fetch_add(&bars[0], 1u, __ATOMIC_ACQ_REL, __HIP_MEMORY_SCOPE_AGENT);
      const unsigned int target = 8u*(unsigned)(p+1);
      while (__hip_atomic_load(&bars[0], __ATOMIC_ACQUIRE, __HIP_MEMORY_SCOPE_AGENT) < target)
        __builtin_amdgcn_s_sleep(2);
    }
    __syncthreads();
    __threadfence();
  }
}

// ---------------------------------------------------------------------------
// K3: pots[b][t][tag] = [h_fw(t), h_bw(t)] @ wde^T + bde (+ boundaries)
// ---------------------------------------------------------------------------
__global__ __launch_bounds__(256) void k_dense(
    const float* __restrict__ h_all, const float* __restrict__ wde,
    const float* __restrict__ bde, const float* __restrict__ lb,
    const float* __restrict__ rb, float* __restrict__ pots)
{
  const int wv   = threadIdx.x >> 6;
  const int lane = threadIdx.x & 63;
  const int tok  = blockIdx.x*4 + wv;          // 0..32767
  const int b = tok >> 9, t = tok & 511;
  const float* hf = h_all + ((size_t)(t+1)*BB + b)*HH;
  const float* hb = h_all + (size_t)(SS+1)*BB*HH + ((size_t)(SS-t)*BB + b)*HH;
  float hr[16];
  *(float4*)&hr[0]  = *(const float4*)&hf[lane*8];
  *(float4*)&hr[4]  = *(const float4*)&hf[lane*8+4];
  *(float4*)&hr[8]  = *(const float4*)&hb[lane*8];
  *(float4*)&hr[12] = *(const float4*)&hb[lane*8+4];
  float s[9];
  #pragma unroll
  for (int tg = 0; tg < 9; ++tg) {
    const float* w0 = wde + tg*1024 + lane*8;
    const float* w1 = w0 + 512;
    const float4 a0 = *(const float4*)w0, a1 = *(const float4*)(w0+4);
    const float4 b0 = *(const float4*)w1, b1 = *(const float4*)(w1+4);
    s[tg] = hr[0]*a0.x + hr[1]*a0.y + hr[2]*a0.z + hr[3]*a0.w
          + hr[4]*a1.x + hr[5]*a1.y + hr[6]*a1.z + hr[7]*a1.w
          + hr[8]*b0.x + hr[9]*b0.y + hr[10]*b0.z + hr[11]*b0.w
          + hr[12]*b1.x + hr[13]*b1.y + hr[14]*b1.z + hr[15]*b1.w;
  }
  #pragma unroll
  for (int tg = 0; tg < 9; ++tg) {
    #pragma unroll
    for (int off = 32; off > 0; off >>= 1) s[tg] += __shfl_xor(s[tg], off, 64);
  }
  if (lane < 9) {
    float v = s[lane] + bde[lane];
    if (t == 0)   v += lb[lane];
    if (t == 511) v += rb[lane];
    pots[(size_t)tok*9 + lane] = v;
  }
}

// ---------------------------------------------------------------------------
// K4: Viterbi decode. One wave per batch row.
// ---------------------------------------------------------------------------
__global__ __launch_bounds__(64) void k_viterbi(
    const float* __restrict__ pots, const float* __restrict__ trans,
    float* __restrict__ dec)
{
  const int b = blockIdx.x;
  const int lane = threadIdx.x;
  __shared__ unsigned char bp[511*9];
  __shared__ unsigned char tl[512];
  __shared__ float af[9];
  const float* pb = pots + (size_t)b*512*9;
  float tr[9];
  #pragma unroll
  for (int i = 0; i < 9; ++i) tr[i] = (lane < 9) ? trans[i*9 + lane] : 0.f;
  float alpha = (lane < 9) ? pb[lane] : -3e38f;
  for (int t = 1; t < 512; ++t) {
    float best = -3e38f; int bi = 0;
    #pragma unroll
    for (int i = 0; i < 9; ++i) {
      const float sc = __shfl(alpha, i, 64) + tr[i];
      if (sc > best) { best = sc; bi = i; }     // strict > keeps first max (jnp.argmax)
    }
    if (lane < 9) {
      bp[(t-1)*9 + lane] = (unsigned char)bi;
      alpha = best + pb[(size_t)t*9 + lane];
    }
  }
  if (lane < 9) af[lane] = alpha;
  __syncthreads();
  if (lane == 0) {
    int tg = 0; float bv = af[0];
    #pragma unroll
    for (int i = 1; i < 9; ++i) if (af[i] > bv) { bv = af[i]; tg = i; }
    tl[511] = (unsigned char)tg;
    for (int t = 510; t >= 0; --t) { tg = bp[t*9 + tg]; tl[t] = (unsigned char)tg; }
  }
  __syncthreads();
  for (int t = lane; t < 512; t += 64) dec[(size_t)b*512 + t] = (float)tl[t];
}

// ---------------------------------------------------------------------------
extern "C" void kernel_launch(void* const* d_in, const int* in_sizes, int n_in,
                              void* d_out, int out_size, void* d_ws, size_t ws_size,
                              hipStream_t stream)
{
  const int*   inputs = (const int*)  d_in[0];
  const float* emb    = (const float*)d_in[1];
  const float* Wf     = (const float*)d_in[2];
  const float* Uf     = (const float*)d_in[3];
  const float* bf     = (const float*)d_in[4];
  const float* Wb     = (const float*)d_in[5];
  const float* Ub     = (const float*)d_in[6];
  const float* bb2    = (const float*)d_in[7];
  const float* Wd     = (const float*)d_in[8];
  const float* bd     = (const float*)d_in[9];
  const float* crfW   = (const float*)d_in[10];
  const float* crfb   = (const float*)d_in[11];
  const float* trans  = (const float*)d_in[12];
  const float* lb     = (const float*)d_in[13];
  const float* rb     = (const float*)d_in[14];

  float* ws   = (float*)d_ws;
  unsigned int* bars = (unsigned int*)d_ws;           // first 1 KB
  float* hall = ws + 256;                             // 2*513*64*512 floats (~134.5 MB)
  float* wde  = hall + (size_t)2*(SS+1)*BB*HH;        // 9216 floats
  float* bde  = wde + 9216;                           // 16 floats

  float* dec  = (float*)d_out;                        // 32768 floats
  float* pots = dec + (size_t)BB*SS;                  // 294912 floats

  hipMemsetAsync(d_ws, 0, 1024, stream);
  hipMemsetAsync(hall, 0, (size_t)BB*HH*sizeof(float), stream);
  hipMemsetAsync(hall + (size_t)(SS+1)*BB*HH, 0, (size_t)BB*HH*sizeof(float), stream);

  k_wde<<<36, 256, 0, stream>>>(Wd, bd, crfW, crfb, wde, bde);

  {
    const int*   a0 = inputs; const float* a1 = emb;
    const float* a2 = Uf;  const float* a3 = Ub;
    const float* a4 = Wf;  const float* a5 = Wb;
    const float* a6 = bf;  const float* a7 = bb2;
    float* a8 = hall; unsigned int* a9 = bars;
    void* args[] = { &a0,&a1,&a2,&a3,&a4,&a5,&a6,&a7,&a8,&a9 };
    if (hipLaunchCooperativeKernel((void*)k_lstm, dim3(NWG), dim3(256),
                                   args, 0, stream) != hipSuccess) {
      // fallback: plain launch (256 WGs on 256 CUs are co-resident in practice)
      k_lstm<<<NWG, 256, 0, stream>>>(inputs, emb, Uf, Ub, Wf, Wb, bf, bb2, hall, bars);
    }
  }

  k_dense<<<8192, 256, 0, stream>>>(hall, wde, bde, lb, rb, pots);
  k_viterbi<<<64, 64, 0, stream>>>(pots, trans, dec);
}

// Round 3
// 20251.312 us; speedup vs baseline: 2.0428x; 2.0428x over previous
//
#include <hip/hip_runtime.h>
#include <hip/hip_bf16.h>
#include <math.h>

#define BB 64
#define SS 512
#define EE 256
#define HH 512
#define GG 2048   // 4H
#define NWG 256

// ---------------------------------------------------------------------------
// K_pre: fold dense + CRF kernel:  wde[tag][k] = sum_m Wd[k][m]*crfW[m][tag]
//        bde[tag] = sum_m bd[m]*crfW[m][tag] + crfb[tag]
// ---------------------------------------------------------------------------
__global__ void k_wde(const float* __restrict__ Wd, const float* __restrict__ bd,
                      const float* __restrict__ crfW, const float* __restrict__ crfb,
                      float* __restrict__ wde, float* __restrict__ bde)
{
  const int idx = blockIdx.x*256 + threadIdx.x;
  if (idx < 9*1024) {
    const int tag = idx >> 10, k = idx & 1023;
    float s = 0.f;
    #pragma unroll
    for (int m = 0; m < 9; ++m) s += Wd[k*9 + m] * crfW[m*9 + tag];
    wde[idx] = s;
  }
  if (idx < 9) {
    float s = crfb[idx];
    #pragma unroll
    for (int m = 0; m < 9; ++m) s += bd[m]*crfW[m*9 + idx];
    bde[idx] = s;
  }
}

// ---------------------------------------------------------------------------
// K2: persistent fused bidirectional LSTM. 256 WGs = 2 dir x 128 col-chunks
// (4 h-cols each), 256 threads. NO __threadfence: h hand-off is coherent via
// agent-scope relaxed atomic stores (write-through to L3) + agent-scope
// relaxed atomic loads (L2-bypass). Two independent per-dir barriers,
// relaxed RMW/polls only (no wbl2 / buffer_inv L2 walks).
// h_all[d][phase 0..512][b][512]; phase 0 = zeros (memset by host).
// ---------------------------------------------------------------------------
__global__ __launch_bounds__(256, 1) void k_lstm(
    const int* __restrict__ inputs, const float* __restrict__ emb,
    const float* __restrict__ Uf, const float* __restrict__ Ub,
    const float* __restrict__ Wf, const float* __restrict__ Wb,
    const float* __restrict__ bf, const float* __restrict__ bb2,
    float* __restrict__ h_all, unsigned int* __restrict__ bars)
{
  const int wg   = blockIdx.x;
  const int d    = wg >> 7;
  const int cblk = wg & 127;                 // h-cols cblk*4 .. +3
  const float* __restrict__ U    = d ? Ub  : Uf;
  const float* __restrict__ W    = d ? Wb  : Wf;
  const float* __restrict__ bias = d ? bb2 : bf;
  float* __restrict__ h_d = h_all + (size_t)d * ((size_t)(SS+1)*BB*HH);
  unsigned int* __restrict__ bar = bars + d*16;   // 64-B separated per dir

  __shared__ float smem[10240];   // overlay: chunk [64 b][128 k] (32KB) / pbuf [512][20] (40KB)
  __shared__ float Wl[4096];      // [cn][i][kcc][jj][g] -> bank-uniform b128 reads
  __shared__ int   tok_l[64];

  const int tid  = threadIdx.x;
  const int bq   = tid >> 6;        // wave id = b quarter
  const int lane = tid & 63;
  const int kcc  = lane & 15;       // 16-way k split
  const int jj   = lane >> 4;       // which of the 4 h-cols

  // stage W slice once: Wl[cn*2048 + i*256 + kcc*16 + jj*4 + g]
  for (int e = 0; e < 16; ++e) {
    const int idx = tid*16 + e;
    const int g   = idx & 3;
    const int j2  = (idx >> 2) & 3;
    const int kc2 = (idx >> 4) & 15;
    const int i2  = (idx >> 8) & 7;
    const int cn2 = (idx >> 11) & 1;
    const int k   = cn2*128 + kc2*8 + i2;
    Wl[idx] = W[(size_t)k*GG + g*512 + cblk*4 + j2];
  }

  // U in registers: ureg[cn*8+i] = gates (i,f,g,o) at k=cn*128+kcc*8+i, col cblk*4+jj
  float4 ureg[32];
  #pragma unroll
  for (int cn = 0; cn < 4; ++cn)
    #pragma unroll
    for (int i = 0; i < 8; ++i) {
      const int k = cn*128 + kcc*8 + i;
      const float* ur = U + (size_t)k*GG + cblk*4 + jj;
      ureg[cn*8+i] = make_float4(ur[0], ur[512], ur[1024], ur[1536]);
    }

  // gate-phase statics (threads 0..127 own (b,col) pairs, fixed across steps)
  const int gq  = tid >> 5;        // 0..3
  const int gbl = (tid >> 2) & 7;  // 0..7
  const int gj  = tid & 3;         // col within chunk
  float bb[4] = {0.f,0.f,0.f,0.f};
  if (tid < 128) {
    #pragma unroll
    for (int g = 0; g < 4; ++g) bb[g] = bias[g*512 + cblk*4 + gj];
  }
  float cst0 = 0.f, cst1 = 0.f;    // c-state for b-half 0 / 1

  // staging statics: thread owns k-span kk..kk+3 of rows b = j*8 + bbase
  const int bbase = tid >> 5;        // 0..7
  const int kk    = (tid & 31) * 4;  // float index within 128-k chunk

  for (int p = 0; p < 512; ++p) {
    const int t = d ? (511 - p) : p;
    const float* __restrict__ hprev = h_d + (size_t)p     * (size_t)(BB*HH);
    float* __restrict__ hnext       = h_d + (size_t)(p+1) * (size_t)(BB*HH);

    if (tid < 64) tok_l[tid] = inputs[tid*SS + t];
    __syncthreads();                 // tok ready; prev-step pbuf reads done

    float4 xr[8];
    unsigned long long hr[16];
    // prefetch chunk 0 (x, normal cached loads)
    #pragma unroll
    for (int j = 0; j < 8; ++j)
      xr[j] = *(const float4*)&emb[(size_t)tok_l[j*8 + bbase]*EE + kk];

    float part[16][4];
    #pragma unroll
    for (int bl=0;bl<16;++bl) { part[bl][0]=0.f; part[bl][1]=0.f; part[bl][2]=0.f; part[bl][3]=0.f; }

    // 6 chunks: cn 0..1 = x@W (K=256), cn 2..5 = h@U (K=512)
    #pragma unroll
    for (int cn = 0; cn < 6; ++cn) {
      // write prefetched regs -> smem [b][k]
      if (cn < 2) {
        #pragma unroll
        for (int j = 0; j < 8; ++j)
          *(float4*)&smem[j*1024 + tid*4] = xr[j];
      } else {
        #pragma unroll
        for (int j = 0; j < 8; ++j) {
          *(unsigned long long*)&smem[j*1024 + tid*4]     = hr[2*j];
          *(unsigned long long*)&smem[j*1024 + tid*4 + 2] = hr[2*j+1];
        }
      }
      // before first h chunk is prefetched: wait for hprev ready (wave 0 polls)
      if (cn == 1 && p && tid < 64) {
        const unsigned int target = 128u*(unsigned)p;
        while (__hip_atomic_load(bar, __ATOMIC_RELAXED, __HIP_MEMORY_SCOPE_AGENT) < target)
          __builtin_amdgcn_s_sleep(1);
      }
      __syncthreads();
      // prefetch next chunk (overlaps with compute below)
      if (cn == 0) {
        #pragma unroll
        for (int j = 0; j < 8; ++j)
          xr[j] = *(const float4*)&emb[(size_t)tok_l[j*8 + bbase]*EE + 128 + kk];
      } else if (cn < 5) {
        const int hc = cn - 1;      // h chunk 0..3 for iteration cn+1
        #pragma unroll
        for (int j = 0; j < 8; ++j) {
          const float* src = &hprev[(size_t)(j*8 + bbase)*HH + hc*128 + kk];
          hr[2*j]   = __hip_atomic_load((const unsigned long long*)src,
                         __ATOMIC_RELAXED, __HIP_MEMORY_SCOPE_AGENT);
          hr[2*j+1] = __hip_atomic_load((const unsigned long long*)(src + 2),
                         __ATOMIC_RELAXED, __HIP_MEMORY_SCOPE_AGENT);
        }
      }
      // compute chunk cn
      if (cn < 2) {
        float4 wv[8];
        #pragma unroll
        for (int i = 0; i < 8; ++i)
          wv[i] = *(const float4*)&Wl[cn*2048 + i*256 + kcc*16 + jj*4];
        #pragma unroll
        for (int bl = 0; bl < 16; ++bl) {
          const float* hrow = &smem[(bq*16 + bl)*128 + kcc*8];
          const float4 ha = *(const float4*)hrow;
          const float4 hb = *(const float4*)(hrow + 4);
          const float hv[8] = {ha.x,ha.y,ha.z,ha.w,hb.x,hb.y,hb.z,hb.w};
          #pragma unroll
          for (int i = 0; i < 8; ++i) {
            part[bl][0] += hv[i]*wv[i].x;
            part[bl][1] += hv[i]*wv[i].y;
            part[bl][2] += hv[i]*wv[i].z;
            part[bl][3] += hv[i]*wv[i].w;
          }
        }
      } else {
        #pragma unroll
        for (int bl = 0; bl < 16; ++bl) {
          const float* hrow = &smem[(bq*16 + bl)*128 + kcc*8];
          const float4 ha = *(const float4*)hrow;
          const float4 hb = *(const float4*)(hrow + 4);
          const float hv[8] = {ha.x,ha.y,ha.z,ha.w,hb.x,hb.y,hb.z,hb.w};
          #pragma unroll
          for (int i = 0; i < 8; ++i) {
            const float4 u = ureg[(cn-2)*8 + i];
            part[bl][0] += hv[i]*u.x;
            part[bl][1] += hv[i]*u.y;
            part[bl][2] += hv[i]*u.z;
            part[bl][3] += hv[i]*u.w;
          }
        }
      }
      __syncthreads();   // compute done; smem reusable
    }

    // reduce 16 k-partials + gates, two b-halves (pbuf overlays smem)
    #pragma unroll
    for (int h = 0; h < 2; ++h) {
      #pragma unroll
      for (int bl = 0; bl < 8; ++bl) {
        const int row = (bq*8 + bl)*16;
        #pragma unroll
        for (int g = 0; g < 4; ++g)
          smem[(row + g*4 + jj)*20 + kcc] = part[h*8 + bl][g];
      }
      __syncthreads();
      if (tid < 128) {
        const int b = gq*16 + h*8 + gbl;
        float z[4];
        #pragma unroll
        for (int g = 0; g < 4; ++g) {
          const float* pr = &smem[((gq*8 + gbl)*16 + g*4 + gj)*20];
          const float4 s0 = *(const float4*)pr;
          const float4 s1 = *(const float4*)(pr+4);
          const float4 s2 = *(const float4*)(pr+8);
          const float4 s3 = *(const float4*)(pr+12);
          z[g] = ((s0.x+s0.y)+(s0.z+s0.w)) + ((s1.x+s1.y)+(s1.z+s1.w))
               + ((s2.x+s2.y)+(s2.z+s2.w)) + ((s3.x+s3.y)+(s3.z+s3.w)) + bb[g];
        }
        const float ig = 1.f/(1.f + expf(-z[0]));
        const float fg = 1.f/(1.f + expf(-z[1]));
        const float tg = tanhf(z[2]);
        const float og = 1.f/(1.f + expf(-z[3]));
        float cs = h ? cst1 : cst0;
        cs = fg*cs + ig*tg;
        if (h) cst1 = cs; else cst0 = cs;
        // write-through store: agent-visible without any L2 flush
        __hip_atomic_store(&hnext[(size_t)b*HH + cblk*4 + gj], og * tanhf(cs),
                           __ATOMIC_RELAXED, __HIP_MEMORY_SCOPE_AGENT);
      }
      __syncthreads();
    }

    // arrive: ensure this WG's h stores reached coherence point, then count
    asm volatile("s_waitcnt vmcnt(0)" ::: "memory");
    __syncthreads();
    if (tid == 0)
      __hip_atomic_fetch_add(bar, 1u, __ATOMIC_RELAXED, __HIP_MEMORY_SCOPE_AGENT);
  }
}

// ---------------------------------------------------------------------------
// K3: pots[b][t][tag] = [h_fw(t), h_bw(t)] @ wde^T + bde (+ boundaries)
// ---------------------------------------------------------------------------
__global__ __launch_bounds__(256) void k_dense(
    const float* __restrict__ h_all, const float* __restrict__ wde,
    const float* __restrict__ bde, const float* __restrict__ lb,
    const float* __restrict__ rb, float* __restrict__ pots)
{
  const int wv   = threadIdx.x >> 6;
  const int lane = threadIdx.x & 63;
  const int tok  = blockIdx.x*4 + wv;          // 0..32767
  const int b = tok >> 9, t = tok & 511;
  const float* hf = h_all + ((size_t)(t+1)*BB + b)*HH;
  const float* hb = h_all + (size_t)(SS+1)*BB*HH + ((size_t)(SS-t)*BB + b)*HH;
  float hr[16];
  *(float4*)&hr[0]  = *(const float4*)&hf[lane*8];
  *(float4*)&hr[4]  = *(const float4*)&hf[lane*8+4];
  *(float4*)&hr[8]  = *(const float4*)&hb[lane*8];
  *(float4*)&hr[12] = *(const float4*)&hb[lane*8+4];
  float s[9];
  #pragma unroll
  for (int tg = 0; tg < 9; ++tg) {
    const float* w0 = wde + tg*1024 + lane*8;
    const float* w1 = w0 + 512;
    const float4 a0 = *(const float4*)w0, a1 = *(const float4*)(w0+4);
    const float4 b0 = *(const float4*)w1, b1 = *(const float4*)(w1+4);
    s[tg] = hr[0]*a0.x + hr[1]*a0.y + hr[2]*a0.z + hr[3]*a0.w
          + hr[4]*a1.x + hr[5]*a1.y + hr[6]*a1.z + hr[7]*a1.w
          + hr[8]*b0.x + hr[9]*b0.y + hr[10]*b0.z + hr[11]*b0.w
          + hr[12]*b1.x + hr[13]*b1.y + hr[14]*b1.z + hr[15]*b1.w;
  }
  #pragma unroll
  for (int tg = 0; tg < 9; ++tg) {
    #pragma unroll
    for (int off = 32; off > 0; off >>= 1) s[tg] += __shfl_xor(s[tg], off, 64);
  }
  if (lane < 9) {
    float v = s[lane] + bde[lane];
    if (t == 0)   v += lb[lane];
    if (t == 511) v += rb[lane];
    pots[(size_t)tok*9 + lane] = v;
  }
}

// ---------------------------------------------------------------------------
// K4: Viterbi decode. One wave per batch row.
// ---------------------------------------------------------------------------
__global__ __launch_bounds__(64) void k_viterbi(
    const float* __restrict__ pots, const float* __restrict__ trans,
    float* __restrict__ dec)
{
  const int b = blockIdx.x;
  const int lane = threadIdx.x;
  __shared__ unsigned char bp[511*9];
  __shared__ unsigned char tl[512];
  __shared__ float af[9];
  const float* pb = pots + (size_t)b*512*9;
  float tr[9];
  #pragma unroll
  for (int i = 0; i < 9; ++i) tr[i] = (lane < 9) ? trans[i*9 + lane] : 0.f;
  float alpha = (lane < 9) ? pb[lane] : -3e38f;
  for (int t = 1; t < 512; ++t) {
    float best = -3e38f; int bi = 0;
    #pragma unroll
    for (int i = 0; i < 9; ++i) {
      const float sc = __shfl(alpha, i, 64) + tr[i];
      if (sc > best) { best = sc; bi = i; }     // strict > keeps first max (jnp.argmax)
    }
    if (lane < 9) {
      bp[(t-1)*9 + lane] = (unsigned char)bi;
      alpha = best + pb[(size_t)t*9 + lane];
    }
  }
  if (lane < 9) af[lane] = alpha;
  __syncthreads();
  if (lane == 0) {
    int tg = 0; float bv = af[0];
    #pragma unroll
    for (int i = 1; i < 9; ++i) if (af[i] > bv) { bv = af[i]; tg = i; }
    tl[511] = (unsigned char)tg;
    for (int t = 510; t >= 0; --t) { tg = bp[t*9 + tg]; tl[t] = (unsigned char)tg; }
  }
  __syncthreads();
  for (int t = lane; t < 512; t += 64) dec[(size_t)b*512 + t] = (float)tl[t];
}

// ---------------------------------------------------------------------------
extern "C" void kernel_launch(void* const* d_in, const int* in_sizes, int n_in,
                              void* d_out, int out_size, void* d_ws, size_t ws_size,
                              hipStream_t stream)
{
  const int*   inputs = (const int*)  d_in[0];
  const float* emb    = (const float*)d_in[1];
  const float* Wf     = (const float*)d_in[2];
  const float* Uf     = (const float*)d_in[3];
  const float* bf     = (const float*)d_in[4];
  const float* Wb     = (const float*)d_in[5];
  const float* Ub     = (const float*)d_in[6];
  const float* bb2    = (const float*)d_in[7];
  const float* Wd     = (const float*)d_in[8];
  const float* bd     = (const float*)d_in[9];
  const float* crfW   = (const float*)d_in[10];
  const float* crfb   = (const float*)d_in[11];
  const float* trans  = (const float*)d_in[12];
  const float* lb     = (const float*)d_in[13];
  const float* rb     = (const float*)d_in[14];

  float* ws   = (float*)d_ws;
  unsigned int* bars = (unsigned int*)d_ws;           // first 1 KB
  float* hall = ws + 256;                             // 2*513*64*512 floats (~134.5 MB)
  float* wde  = hall + (size_t)2*(SS+1)*BB*HH;        // 9216 floats
  float* bde  = wde + 9216;                           // 16 floats

  float* dec  = (float*)d_out;                        // 32768 floats
  float* pots = dec + (size_t)BB*SS;                  // 294912 floats

  hipMemsetAsync(d_ws, 0, 1024, stream);
  hipMemsetAsync(hall, 0, (size_t)BB*HH*sizeof(float), stream);
  hipMemsetAsync(hall + (size_t)(SS+1)*BB*HH, 0, (size_t)BB*HH*sizeof(float), stream);

  k_wde<<<36, 256, 0, stream>>>(Wd, bd, crfW, crfb, wde, bde);

  {
    const int*   a0 = inputs; const float* a1 = emb;
    const float* a2 = Uf;  const float* a3 = Ub;
    const float* a4 = Wf;  const float* a5 = Wb;
    const float* a6 = bf;  const float* a7 = bb2;
    float* a8 = hall; unsigned int* a9 = bars;
    void* args[] = { &a0,&a1,&a2,&a3,&a4,&a5,&a6,&a7,&a8,&a9 };
    if (hipLaunchCooperativeKernel((void*)k_lstm, dim3(NWG), dim3(256),
                                   args, 0, stream) != hipSuccess) {
      k_lstm<<<NWG, 256, 0, stream>>>(inputs, emb, Uf, Ub, Wf, Wb, bf, bb2, hall, bars);
    }
  }

  k_dense<<<8192, 256, 0, stream>>>(hall, wde, bde, lb, rb, pots);
  k_viterbi<<<64, 64, 0, stream>>>(pots, trans, dec);
}